// Round 6
// baseline (492.655 us; speedup 1.0000x reference)
//
#include <hip/hip_runtime.h>
#include <hip/hip_bf16.h>

// Linear attention (BaseMultiHeadAttention_21105469292684)
// M=16, N=2048, C=512, H=8, D=64.
//   K0a: proj weights fp32 -> bf16 fragment-major (validated r2/r4)
//   K0b: Wo fp32 -> bf16 transposed WoT[c][k]
//   K1 : Q/K/V: zero-barrier K-loop, B resident in 128 VGPRs/wave, A direct
//        from fp32 X (L1-shared across 4 waves), softmax via 2-wave exchange
//   K2 : kv partials = K_h^T V_h over n-chunks (fp32)
//   K3 : Wfused = blockdiag(kv) @ Wo, emitted fragment-major (validated r4)
//   K4 : out = Q @ Wfused[m] + bo, same zero-barrier structure, fp32 out

typedef __bf16 bf16;
typedef __bf16 bf16x8 __attribute__((ext_vector_type(8)));
typedef __bf16 bf16x4 __attribute__((ext_vector_type(4)));
typedef float  f32x4  __attribute__((ext_vector_type(4)));

#define MFMA16(a, b, c) __builtin_amdgcn_mfma_f32_16x16x32_bf16((a), (b), (c), 0, 0, 0)

__device__ inline bf16x8 cvt8(float4 a, float4 b) {
  bf16x8 h;
  h[0] = (bf16)a.x; h[1] = (bf16)a.y; h[2] = (bf16)a.z; h[3] = (bf16)a.w;
  h[4] = (bf16)b.x; h[5] = (bf16)b.y; h[6] = (bf16)b.z; h[7] = (bf16)b.w;
  return h;
}

// ---------------- K0a: proj weights -> fragment-major bf16 ----------------
// Layout (elements): [cg 4][kt64 8][ksub 2][cb7 8][lane 64][8]
//   element W[k][c]: cg=c>>7, kt64=k>>6, ksub=(k>>5)&1, cb7=(c>>4)&7,
//                    lane=((k>>3)&3)*16 + (c&15), last = k&7
__global__ __launch_bounds__(256) void k_prep_frag(const float* __restrict__ w0, const float* __restrict__ w1,
                                                   const float* __restrict__ w2,
                                                   bf16* __restrict__ f0, bf16* __restrict__ f1,
                                                   bf16* __restrict__ f2)
{
  const float* W = (blockIdx.z == 0) ? w0 : (blockIdx.z == 1) ? w1 : w2;
  bf16*        F = (blockIdx.z == 0) ? f0 : (blockIdx.z == 1) ? f1 : f2;
  __shared__ float lds[64][68];
  const int t = threadIdx.x;
  const int bx = blockIdx.x, by = blockIdx.y;   // bx: k-tile(64), by: c-tile(64)
  {
    const int r = t >> 2, c0 = (t & 3) << 4;
    const float* src = W + (size_t)(bx * 64 + r) * 512 + by * 64 + c0;
    float4 a = ((const float4*)src)[0], b = ((const float4*)src)[1];
    float4 c = ((const float4*)src)[2], d = ((const float4*)src)[3];
    *(float4*)&lds[r][c0 + 0]  = a; *(float4*)&lds[r][c0 + 4]  = b;
    *(float4*)&lds[r][c0 + 8]  = c; *(float4*)&lds[r][c0 + 12] = d;
  }
  __syncthreads();
#pragma unroll
  for (int it = 0; it < 2; ++it) {
    const int ch = t + it * 256;
    const int kc = ch >> 6, cc = ch & 63;       // k-octet, c within tile
    bf16x8 v;
#pragma unroll
    for (int j = 0; j < 8; ++j) v[j] = (bf16)lds[kc * 8 + j][cc];
    const int cg   = by >> 1;
    const int cb7  = ((by & 1) << 2) | (cc >> 4);
    const int ksub = kc >> 2, g = kc & 3, li = cc & 15;
    const size_t off = (size_t)cg * 65536 + (size_t)bx * 8192 + ksub * 4096 + cb7 * 512 + (g * 16 + li) * 8;
    *(bf16x8*)(F + off) = v;
  }
}

// ---------------- K0b: Wo -> transposed bf16 WoT[c][k] ----------------
__global__ __launch_bounds__(256) void k_prep_wo(const float* __restrict__ W, bf16* __restrict__ T)
{
  __shared__ float lds[64][68];
  const int t = threadIdx.x;
  const int r = t >> 2, c0 = (t & 3) << 4;
  const float* src = W + (size_t)(blockIdx.x * 64 + r) * 512 + blockIdx.y * 64 + c0;
  float4 f0 = ((const float4*)src)[0];
  float4 f1 = ((const float4*)src)[1];
  float4 f2 = ((const float4*)src)[2];
  float4 f3 = ((const float4*)src)[3];
  *(float4*)&lds[r][c0 + 0]  = f0;
  *(float4*)&lds[r][c0 + 4]  = f1;
  *(float4*)&lds[r][c0 + 8]  = f2;
  *(float4*)&lds[r][c0 + 12] = f3;
  __syncthreads();
  bf16 v[16];
#pragma unroll
  for (int s = 0; s < 16; ++s) v[s] = (bf16)lds[c0 + s][r];
  bf16* dst = T + (size_t)(blockIdx.y * 64 + r) * 512 + blockIdx.x * 64 + c0;
  *(bf16x8*)&dst[0] = *(bf16x8*)&v[0];
  *(bf16x8*)&dst[8] = *(bf16x8*)&v[8];
}

// ---------------- K1: zero-barrier projection + per-head softmax ----------------
// 6144 blocks x 256 thr (4 waves). Block = 64 rows x 128 cols.
// Wave w: 64 rows x 32 cols, B resident in regs (16 kt x 2 ct frags = 128 VGPR).
// All 4 waves read the SAME 64 A-rows (L1-served). Softmax pairs waves (w, w^1).
__global__ __launch_bounds__(256, 2) void k_qkv(const float* __restrict__ xq, const float* __restrict__ xk,
                                                const float* __restrict__ xv,
                                                const bf16* __restrict__ Fq, const bf16* __restrict__ Fk,
                                                const bf16* __restrict__ Fv,
                                                bf16* __restrict__ Qo, bf16* __restrict__ Ko,
                                                bf16* __restrict__ Vo)
{
  const int wg = blockIdx.x;
  const int o  = (wg & 7) * 768 + (wg >> 3);   // 6144 = 768*8, bijective XCD chunking
  const int proj  = o >> 11;                   // 2048 blocks per projection
  const int rem   = o & 2047;
  const int strip = rem >> 2, cgrp = rem & 3;  // 4 col-group blocks of a strip adjacent -> same XCD

  const float* X  = (proj == 0) ? xq : (proj == 1) ? xk : xv;
  const bf16*  F  = (proj == 0) ? Fq : (proj == 1) ? Fk : Fv;
  bf16*       OUT = (proj == 0) ? Qo : (proj == 1) ? Ko : Vo;

  const int t = threadIdx.x, lane = t & 63, w = t >> 6;
  const int g = lane >> 4, li = lane & 15;

  // ---- resident B fragments: 32 cols x K=512 ----
  bf16x8 bres[16][2];
  const bf16* Fb = F + (size_t)cgrp * 65536 + (w * 2) * 512 + lane * 8;
#pragma unroll
  for (int kk = 0; kk < 16; ++kk) {
    const bf16* p = Fb + (kk >> 1) * 8192 + (kk & 1) * 4096;
    bres[kk][0] = *(const bf16x8*)(p);
    bres[kk][1] = *(const bf16x8*)(p + 512);
  }

  const float* ap = X + (size_t)(strip * 64 + li) * 512 + g * 8;

  f32x4 acc[4][2] = {};

#pragma unroll
  for (int kt = 0; kt < 16; ++kt) {
    bf16x8 af[4];
#pragma unroll
    for (int rt = 0; rt < 4; ++rt) {
      const float* p = ap + rt * 8192 + kt * 32;
      float4 a = ((const float4*)p)[0];
      float4 b = ((const float4*)p)[1];
      af[rt] = cvt8(a, b);
    }
#pragma unroll
    for (int rt = 0; rt < 4; ++rt) {
      acc[rt][0] = MFMA16(af[rt], bres[kt][0], acc[rt][0]);
      acc[rt][1] = MFMA16(af[rt], bres[kt][1], acc[rt][1]);
    }
  }

  const int colbase = cgrp * 128 + w * 32;
  __shared__ float exm[4][64];
  __shared__ float exs[4][64];

  if (proj < 2) {
    // stage 1: per-wave 32-col max per row, exchange with partner wave
    float pm[4][4];
#pragma unroll
    for (int rt = 0; rt < 4; ++rt)
#pragma unroll
      for (int q = 0; q < 4; ++q) {
        float mx = fmaxf(acc[rt][0][q], acc[rt][1][q]);
        mx = fmaxf(mx, __shfl_xor(mx, 1));
        mx = fmaxf(mx, __shfl_xor(mx, 2));
        mx = fmaxf(mx, __shfl_xor(mx, 4));
        mx = fmaxf(mx, __shfl_xor(mx, 8));
        pm[rt][q] = mx;
      }
    if (li == 0) {
#pragma unroll
      for (int rt = 0; rt < 4; ++rt)
#pragma unroll
        for (int q = 0; q < 4; ++q)
          exm[w][rt * 16 + g * 4 + q] = pm[rt][q];
    }
    __syncthreads();
    // stage 2: exp with combined max, per-wave partial sums, exchange
    float ps[4][4];
#pragma unroll
    for (int rt = 0; rt < 4; ++rt)
#pragma unroll
      for (int q = 0; q < 4; ++q) {
        const int r = rt * 16 + g * 4 + q;
        float mx = fmaxf(exm[w][r], exm[w ^ 1][r]);
        float e0 = __expf(acc[rt][0][q] - mx);
        float e1 = __expf(acc[rt][1][q] - mx);
        acc[rt][0][q] = e0; acc[rt][1][q] = e1;
        float s = e0 + e1;
        s += __shfl_xor(s, 1); s += __shfl_xor(s, 2);
        s += __shfl_xor(s, 4); s += __shfl_xor(s, 8);
        ps[rt][q] = s;
      }
    if (li == 0) {
#pragma unroll
      for (int rt = 0; rt < 4; ++rt)
#pragma unroll
        for (int q = 0; q < 4; ++q)
          exs[w][rt * 16 + g * 4 + q] = ps[rt][q];
    }
    __syncthreads();
    const float scale = (proj == 0) ? 0.125f : 1.0f;
#pragma unroll
    for (int rt = 0; rt < 4; ++rt)
#pragma unroll
      for (int q = 0; q < 4; ++q) {
        const int r = rt * 16 + g * 4 + q;
        const float inv = scale / (exs[w][r] + exs[w ^ 1][r]);
        bf16* op = OUT + (size_t)(strip * 64 + r) * 512 + colbase + li;
        op[0]  = (bf16)(acc[rt][0][q] * inv);
        op[16] = (bf16)(acc[rt][1][q] * inv);
      }
  } else {
#pragma unroll
    for (int rt = 0; rt < 4; ++rt)
#pragma unroll
      for (int q = 0; q < 4; ++q) {
        const int r = rt * 16 + g * 4 + q;
        bf16* op = OUT + (size_t)(strip * 64 + r) * 512 + colbase + li;
        op[0]  = (bf16)acc[rt][0][q];
        op[16] = (bf16)acc[rt][1][q];
      }
  }
}

// ---------------- K2: kv partials = K_h^T V_h over an n-chunk ----------------
__global__ __launch_bounds__(256) void k_kv(const bf16* __restrict__ K, const bf16* __restrict__ V,
                                            float* __restrict__ kvp)
{
  const int mh = blockIdx.x, m = mh >> 3, h = mh & 7;
  const int ns = blockIdx.y;
  __shared__ bf16 Kt[64][40];
  __shared__ bf16 Vt[64][40];
  const int t = threadIdx.x, lane = t & 63, wave = t >> 6;
  const int dq = wave >> 1, eq = wave & 1;
  const int g = lane >> 4, li = lane & 15;
  const int tn = t & 31, d0 = (t >> 5) << 3;
  const size_t rowbase = (size_t)m * 2048 + ns * 512;

  f32x4 acc[2][2] = {};

  for (int nt = 0; nt < 16; ++nt) {
    __syncthreads();
    {
      bf16x8 kr = *(const bf16x8*)(K + (rowbase + nt * 32 + tn) * 512 + h * 64 + d0);
      bf16x8 vr = *(const bf16x8*)(V + (rowbase + nt * 32 + tn) * 512 + h * 64 + d0);
#pragma unroll
      for (int j = 0; j < 8; ++j) Kt[d0 + j][tn] = kr[j];
#pragma unroll
      for (int j = 0; j < 8; ++j) Vt[d0 + j][tn] = vr[j];
    }
    __syncthreads();
    bf16x8 af[2], bfr[2];
#pragma unroll
    for (int dt = 0; dt < 2; ++dt) af[dt]  = *(const bf16x8*)&Kt[dq * 32 + dt * 16 + li][g * 8];
#pragma unroll
    for (int et = 0; et < 2; ++et) bfr[et] = *(const bf16x8*)&Vt[eq * 32 + et * 16 + li][g * 8];
#pragma unroll
    for (int dt = 0; dt < 2; ++dt)
#pragma unroll
      for (int et = 0; et < 2; ++et)
        acc[dt][et] = MFMA16(af[dt], bfr[et], acc[dt][et]);
  }

  float* o = kvp + ((size_t)mh * 4 + ns) * 4096;
#pragma unroll
  for (int dt = 0; dt < 2; ++dt)
#pragma unroll
    for (int et = 0; et < 2; ++et)
#pragma unroll
      for (int q = 0; q < 4; ++q) {
        const int d = dq * 32 + dt * 16 + g * 4 + q;
        const int e = eq * 32 + et * 16 + li;
        o[d * 64 + e] = acc[dt][et][q];
      }
}

// ---------------- K3: Wfused = blockdiag(kv) @ Wo, frag-major out (validated r4) ----------------
__global__ __launch_bounds__(512) void k_wfused(const float* __restrict__ kvp, const bf16* __restrict__ WoT,
                                                bf16* __restrict__ WfF)
{
  const int mh = blockIdx.x, m = mh >> 3, h = mh & 7;
  __shared__ bf16 kvs[64][72];
  const int t = threadIdx.x, lane = t & 63, wv = t >> 6;
  const int g = lane >> 4, li = lane & 15;
  {
    const int d = t >> 3, e0 = (t & 7) << 3;
    const float* p = kvp + (size_t)mh * 16384 + d * 64 + e0;
#pragma unroll
    for (int j = 0; j < 8; ++j) {
      float s = p[j] + p[4096 + j] + p[8192 + j] + p[12288 + j];
      kvs[d][e0 + j] = (bf16)s;
    }
  }
  __syncthreads();
  f32x4 acc[4][4] = {};
#pragma unroll
  for (int kk = 0; kk < 2; ++kk) {
    bf16x8 a_kv[4], b_wo[4];
#pragma unroll
    for (int rt = 0; rt < 4; ++rt)
      a_kv[rt] = *(const bf16x8*)&kvs[rt * 16 + li][kk * 32 + g * 8];
#pragma unroll
    for (int ct = 0; ct < 4; ++ct) {
      const int cout = wv * 64 + ct * 16 + li;
      b_wo[ct] = *(const bf16x8*)(WoT + (size_t)cout * 512 + h * 64 + kk * 32 + g * 8);
    }
#pragma unroll
    for (int rt = 0; rt < 4; ++rt)
#pragma unroll
      for (int ct = 0; ct < 4; ++ct)
        acc[rt][ct] = MFMA16(a_kv[rt], b_wo[ct], acc[rt][ct]);
  }
  // emit fragment-major: k = h*64 + rt*16 + g*4 + q, col = wv*64 + ct*16 + li
  bf16* o = WfF + (size_t)m * 262144;
#pragma unroll
  for (int rt = 0; rt < 4; ++rt)
#pragma unroll
    for (int ct = 0; ct < 4; ++ct) {
      const int cgct  = wv * 4 + ct;                  // 0..31
      const int cg    = cgct >> 3, cb7 = cgct & 7;
      const int lane2 = ((rt & 1) * 2 + (g >> 1)) * 16 + li;
      const size_t off = (size_t)cg * 65536 + (size_t)h * 8192 + (rt >> 1) * 4096
                       + cb7 * 512 + lane2 * 8 + (g & 1) * 4;
      bf16x4 v;
#pragma unroll
      for (int q = 0; q < 4; ++q) v[q] = (bf16)acc[rt][ct][q];
      *(bf16x4*)(o + off) = v;
    }
}

// ---------------- K4: out = Q @ Wfused[m] + bo, zero-barrier ----------------
// 2048 blocks x 256 thr (4 waves). Block = 64 rows x 128 cols; wave 64x32, B resident.
__global__ __launch_bounds__(256, 2) void k_out(const bf16* __restrict__ Q, const bf16* __restrict__ WfF,
                                                const float* __restrict__ bo, float* __restrict__ out)
{
  const int wg = blockIdx.x;
  const int o  = (wg & 7) * 256 + (wg >> 3);   // 2048 = 256*8, bijective
  const int strip = o >> 2, cgrp = o & 3;
  const int m = strip >> 5;                     // 32 strips (of 64 rows) per m
  const bf16* Fm = WfF + (size_t)m * 262144;

  const int t = threadIdx.x, lane = t & 63, w = t >> 6;
  const int g = lane >> 4, li = lane & 15;

  bf16x8 bres[16][2];
  const bf16* Fb = Fm + (size_t)cgrp * 65536 + (w * 2) * 512 + lane * 8;
#pragma unroll
  for (int kk = 0; kk < 16; ++kk) {
    const bf16* p = Fb + (kk >> 1) * 8192 + (kk & 1) * 4096;
    bres[kk][0] = *(const bf16x8*)(p);
    bres[kk][1] = *(const bf16x8*)(p + 512);
  }

  const bf16* ap = Q + (size_t)(strip * 64 + li) * 512 + g * 8;

  f32x4 acc[4][2] = {};

#pragma unroll
  for (int kt = 0; kt < 16; ++kt) {
    bf16x8 af[4];
#pragma unroll
    for (int rt = 0; rt < 4; ++rt)
      af[rt] = *(const bf16x8*)(ap + rt * 8192 + kt * 32);
#pragma unroll
    for (int rt = 0; rt < 4; ++rt) {
      acc[rt][0] = MFMA16(af[rt], bres[kt][0], acc[rt][0]);
      acc[rt][1] = MFMA16(af[rt], bres[kt][1], acc[rt][1]);
    }
  }

  const int colbase = cgrp * 128 + w * 32;
  const float b0 = bo[colbase + li], b1 = bo[colbase + 16 + li];
#pragma unroll
  for (int rt = 0; rt < 4; ++rt)
#pragma unroll
    for (int q = 0; q < 4; ++q) {
      float* op = out + (size_t)(strip * 64 + rt * 16 + g * 4 + q) * 512 + colbase + li;
      op[0]  = acc[rt][0][q] + b0;
      op[16] = acc[rt][1][q] + b1;
    }
}

// ---------------- host ----------------
extern "C" void kernel_launch(void* const* d_in, const int* in_sizes, int n_in,
                              void* d_out, int out_size, void* d_ws, size_t ws_size,
                              hipStream_t stream)
{
  const float* xq = (const float*)d_in[0];
  const float* xk = (const float*)d_in[1];
  const float* xv = (const float*)d_in[2];
  const float* Wq = (const float*)d_in[3];
  const float* Wk = (const float*)d_in[4];
  const float* Wv = (const float*)d_in[5];
  const float* Wo = (const float*)d_in[6];
  const float* bo = (const float*)d_in[7];
  float* out = (float*)d_out;

  char* ws = (char*)d_ws;
  const size_t WT_BYTES  = 512 * 512 * 2;           // 512 KiB
  const size_t QKV_BYTES = (size_t)32768 * 512 * 2; // 32 MiB
  bf16*  WFq = (bf16*)(ws);
  bf16*  WFk = (bf16*)(ws + WT_BYTES);
  bf16*  WFv = (bf16*)(ws + 2 * WT_BYTES);
  bf16*  WoT = (bf16*)(ws + 3 * WT_BYTES);
  bf16*  Qb  = (bf16*)(ws + 4 * WT_BYTES);
  bf16*  Kb  = (bf16*)(ws + 4 * WT_BYTES + QKV_BYTES);
  bf16*  Vb  = (bf16*)(ws + 4 * WT_BYTES + 2 * QKV_BYTES);
  float* kvp = (float*)(ws + 4 * WT_BYTES + 3 * QKV_BYTES);  // 8 MiB
  bf16*  WfF = Kb;  // overlay: Kb dead after k_kv

  k_prep_frag<<<dim3(8, 8, 3), 256, 0, stream>>>(Wq, Wk, Wv, WFq, WFk, WFv);
  k_prep_wo  <<<dim3(8, 8),    256, 0, stream>>>(Wo, WoT);
  k_qkv      <<<dim3(6144),    256, 0, stream>>>(xq, xk, xv, WFq, WFk, WFv, Qb, Kb, Vb);
  k_kv       <<<dim3(128, 4),  256, 0, stream>>>(Kb, Vb, kvp);
  k_wfused   <<<dim3(128),     512, 0, stream>>>(kvp, WoT, WfF);
  k_out      <<<dim3(2048),    256, 0, stream>>>(Qb, WfF, bo, out);
}

// Round 7
// 166.857 us; speedup vs baseline: 2.9526x; 2.9526x over previous
//
#include <hip/hip_runtime.h>
#include <hip/hip_bf16.h>

// Linear attention (BaseMultiHeadAttention_21105469292684)
// M=16, N=2048, C=512, H=8, D=64.
//   K0 : weights fp32 -> bf16 transposed WT[col][k] (all 4)
//   K1 : Q/K/V = softmax-ish(x @ W): r1 structure (BM=64, BN=512, BK=32, 8 waves)
//        + async A-load (T14) + B via global_load_lds w/ involution swizzle
//   K2 : kv partials = K_h^T V_h over n-chunks (fp32)
//   K3 : WfusedT[m][c][r] = sum_e kv[m,h,d,e] * Wo[h*64+e][c]  (bf16)
//   K4 : out = Q @ Wfused[m] + bo: BM=64, BN=512, BK=64, both operands gload_lds

typedef __bf16 bf16;
typedef __bf16 bf16x8 __attribute__((ext_vector_type(8)));
typedef __bf16 bf16x4 __attribute__((ext_vector_type(4)));
typedef float  f32x4  __attribute__((ext_vector_type(4)));

#define MFMA16(a, b, c) __builtin_amdgcn_mfma_f32_16x16x32_bf16((a), (b), (c), 0, 0, 0)

__device__ inline void glds16(const void* g, void* l) {
  __builtin_amdgcn_global_load_lds((const __attribute__((address_space(1))) void*)g,
                                   (__attribute__((address_space(3))) void*)l, 16, 0, 0);
}

// ---------------- K0: transpose + convert weights (512x512 each) ----------------
__global__ __launch_bounds__(256) void k_prep(const float* __restrict__ w0, const float* __restrict__ w1,
                                              const float* __restrict__ w2, const float* __restrict__ w3,
                                              bf16* __restrict__ t0, bf16* __restrict__ t1,
                                              bf16* __restrict__ t2, bf16* __restrict__ t3)
{
  const float* W = (blockIdx.z == 0) ? w0 : (blockIdx.z == 1) ? w1 : (blockIdx.z == 2) ? w2 : w3;
  bf16*        T = (blockIdx.z == 0) ? t0 : (blockIdx.z == 1) ? t1 : (blockIdx.z == 2) ? t2 : t3;
  __shared__ float lds[64][68];
  const int t = threadIdx.x;
  const int r = t >> 2, c0 = (t & 3) << 4;
  const float* src = W + (size_t)(blockIdx.x * 64 + r) * 512 + blockIdx.y * 64 + c0;
  float4 f0 = ((const float4*)src)[0];
  float4 f1 = ((const float4*)src)[1];
  float4 f2 = ((const float4*)src)[2];
  float4 f3 = ((const float4*)src)[3];
  *(float4*)&lds[r][c0 + 0]  = f0;
  *(float4*)&lds[r][c0 + 4]  = f1;
  *(float4*)&lds[r][c0 + 8]  = f2;
  *(float4*)&lds[r][c0 + 12] = f3;
  __syncthreads();
  bf16 v[16];
#pragma unroll
  for (int s = 0; s < 16; ++s) v[s] = (bf16)lds[c0 + s][r];
  bf16* dst = T + (size_t)(blockIdx.y * 64 + r) * 512 + blockIdx.x * 64 + c0;
  *(bf16x8*)&dst[0] = *(bf16x8*)&v[0];
  *(bf16x8*)&dst[8] = *(bf16x8*)&v[8];
}

// ---------------- K1: fused projection + per-head softmax ----------------
// grid (512,1,3): 512 row-blocks of 64 rows, z = proj. 512 thr = 8 waves; wave = head.
// A: fp32->bf16 reg-staged into As[64][40] (2-way banks = free).
// B: global_load_lds into linear Bs[512][32], involution chunk swizzle:
//    storage: row r slot s holds W chunk s ^ ((r>>1)&3); read slot = g ^ ((li>>1)&3).
__global__ __launch_bounds__(512) void k_qkv(const float* __restrict__ xq, const float* __restrict__ xk,
                                             const float* __restrict__ xv,
                                             const bf16* __restrict__ WqT, const bf16* __restrict__ WkT,
                                             const bf16* __restrict__ WvT,
                                             bf16* __restrict__ Qo, bf16* __restrict__ Ko,
                                             bf16* __restrict__ Vo)
{
  const int proj = blockIdx.z;
  const float* X  = (proj == 0) ? xq  : (proj == 1) ? xk  : xv;
  const bf16*  WT = (proj == 0) ? WqT : (proj == 1) ? WkT : WvT;
  bf16*       OUT = (proj == 0) ? Qo  : (proj == 1) ? Ko  : Vo;

  __shared__ bf16 As[64][40];     // 5 KB
  __shared__ bf16 Bs[512 * 32];   // 32 KB, linear (gload_lds dest)

  const int t = threadIdx.x;
  const int lane = t & 63, w = t >> 6;          // w = head
  const int g = lane >> 4, li = lane & 15;
  const size_t arow = (size_t)blockIdx.x * 64;

  // A staging: thread -> row t>>3, 4 floats at col (t&7)*4
  const int ar = t >> 3, ac = (t & 7) << 2;
  const float* xp = X + (arow + ar) * 512 + ac;

  // B staging source (per lane, involution pre-swizzled): issue j covers rows w*64+j*16..+16
  const bf16* bsrc = WT + (size_t)(w * 64 + (lane >> 2)) * 512
                        + (((lane & 3) ^ ((lane >> 3) & 3)) << 3);
  char* bdst = (char*)&Bs[0] + w * 4096;        // wave-uniform dest base
  const int bslot = g ^ ((li >> 1) & 3);        // read-side slot

  f32x4 acc[4][4] = {};
  float4 xa = ((const float4*)xp)[0];           // kt=0 A fragment

  for (int kt = 0; kt < 16; ++kt) {
    __syncthreads();                            // (1) readers done with prev tiles
    {  // write A (cvt in reg, 8B ds_write)
      bf16x4 h; h[0] = (bf16)xa.x; h[1] = (bf16)xa.y; h[2] = (bf16)xa.z; h[3] = (bf16)xa.w;
      *(bf16x4*)&As[ar][ac] = h;
    }
#pragma unroll
    for (int j = 0; j < 4; ++j)                 // stage B slice (4 x 1KB per wave)
      glds16(bsrc + (size_t)j * 16 * 512 + kt * 32, bdst + j * 1024);
    __syncthreads();                            // (2) staging visible (drains glds)
    if (kt < 15)                                // T14: next A-load issues under MFMA phase
      xa = ((const float4*)(xp + (kt + 1) * 32))[0];
    bf16x8 af[4], bfr[4];
#pragma unroll
    for (int rt = 0; rt < 4; ++rt) af[rt] = *(const bf16x8*)&As[rt * 16 + li][g * 8];
#pragma unroll
    for (int ct = 0; ct < 4; ++ct)
      bfr[ct] = *(const bf16x8*)&Bs[(w * 64 + ct * 16 + li) * 32 + bslot * 8];
#pragma unroll
    for (int rt = 0; rt < 4; ++rt)
#pragma unroll
      for (int ct = 0; ct < 4; ++ct)
        acc[rt][ct] = MFMA16(af[rt], bfr[ct], acc[rt][ct]);
  }

  // epilogue: softmax over the 64 head columns (rows = rt*16+g*4+q, cols = ct*16+li)
#pragma unroll
  for (int rt = 0; rt < 4; ++rt) {
#pragma unroll
    for (int q = 0; q < 4; ++q) {
      float v0 = acc[rt][0][q], v1 = acc[rt][1][q], v2 = acc[rt][2][q], v3 = acc[rt][3][q];
      if (proj < 2) {
        float mx = fmaxf(fmaxf(v0, v1), fmaxf(v2, v3));
        mx = fmaxf(mx, __shfl_xor(mx, 1));
        mx = fmaxf(mx, __shfl_xor(mx, 2));
        mx = fmaxf(mx, __shfl_xor(mx, 4));
        mx = fmaxf(mx, __shfl_xor(mx, 8));
        v0 = __expf(v0 - mx); v1 = __expf(v1 - mx); v2 = __expf(v2 - mx); v3 = __expf(v3 - mx);
        float s = v0 + v1 + v2 + v3;
        s += __shfl_xor(s, 1); s += __shfl_xor(s, 2); s += __shfl_xor(s, 4); s += __shfl_xor(s, 8);
        const float inv = (proj == 0 ? 0.125f : 1.0f) / s;
        v0 *= inv; v1 *= inv; v2 *= inv; v3 *= inv;
      }
      bf16* o = OUT + (arow + rt * 16 + g * 4 + q) * 512 + w * 64 + li;
      o[0] = (bf16)v0; o[16] = (bf16)v1; o[32] = (bf16)v2; o[48] = (bf16)v3;
    }
  }
}

// ---------------- K2: kv partials = K_h^T V_h over an n-chunk ----------------
__global__ __launch_bounds__(256) void k_kv(const bf16* __restrict__ K, const bf16* __restrict__ V,
                                            float* __restrict__ kvp)
{
  const int mh = blockIdx.x, m = mh >> 3, h = mh & 7;
  const int ns = blockIdx.y;
  __shared__ bf16 Kt[64][40];
  __shared__ bf16 Vt[64][40];
  const int t = threadIdx.x, lane = t & 63, wave = t >> 6;
  const int dq = wave >> 1, eq = wave & 1;
  const int g = lane >> 4, li = lane & 15;
  const int tn = t & 31, d0 = (t >> 5) << 3;
  const size_t rowbase = (size_t)m * 2048 + ns * 512;

  f32x4 acc[2][2] = {};

  for (int nt = 0; nt < 16; ++nt) {
    __syncthreads();
    {
      bf16x8 kr = *(const bf16x8*)(K + (rowbase + nt * 32 + tn) * 512 + h * 64 + d0);
      bf16x8 vr = *(const bf16x8*)(V + (rowbase + nt * 32 + tn) * 512 + h * 64 + d0);
#pragma unroll
      for (int j = 0; j < 8; ++j) Kt[d0 + j][tn] = kr[j];
#pragma unroll
      for (int j = 0; j < 8; ++j) Vt[d0 + j][tn] = vr[j];
    }
    __syncthreads();
    bf16x8 af[2], bfr[2];
#pragma unroll
    for (int dt = 0; dt < 2; ++dt) af[dt]  = *(const bf16x8*)&Kt[dq * 32 + dt * 16 + li][g * 8];
#pragma unroll
    for (int et = 0; et < 2; ++et) bfr[et] = *(const bf16x8*)&Vt[eq * 32 + et * 16 + li][g * 8];
#pragma unroll
    for (int dt = 0; dt < 2; ++dt)
#pragma unroll
      for (int et = 0; et < 2; ++et)
        acc[dt][et] = MFMA16(af[dt], bfr[et], acc[dt][et]);
  }

  float* o = kvp + ((size_t)mh * 4 + ns) * 4096;
#pragma unroll
  for (int dt = 0; dt < 2; ++dt)
#pragma unroll
    for (int et = 0; et < 2; ++et)
#pragma unroll
      for (int q = 0; q < 4; ++q) {
        const int d = dq * 32 + dt * 16 + g * 4 + q;
        const int e = eq * 32 + et * 16 + li;
        o[d * 64 + e] = acc[dt][et][q];
      }
}

// ---------------- K3: WfusedT[m][c][r=h*64+d] = sum_e kv[d][e] * WoT[c][h*64+e] ----------------
__global__ __launch_bounds__(512) void k_wfused(const float* __restrict__ kvp, const bf16* __restrict__ WoT,
                                                bf16* __restrict__ WfT)
{
  const int mh = blockIdx.x, m = mh >> 3, h = mh & 7;
  __shared__ bf16 kvs[64][72];
  const int t = threadIdx.x, lane = t & 63, wave = t >> 6;
  const int g = lane >> 4, li = lane & 15;
  {
    const int d = t >> 3, e0 = (t & 7) << 3;
    const float* p = kvp + (size_t)mh * 16384 + d * 64 + e0;
#pragma unroll
    for (int j = 0; j < 8; ++j) {
      float s = p[j] + p[4096 + j] + p[8192 + j] + p[12288 + j];
      kvs[d][e0 + j] = (bf16)s;
    }
  }
  __syncthreads();
  f32x4 acc[4][4] = {};
#pragma unroll
  for (int kk = 0; kk < 2; ++kk) {
    bf16x8 af[4], bfr[4];
#pragma unroll
    for (int rt = 0; rt < 4; ++rt) {
      const int c = wave * 64 + rt * 16 + li;
      af[rt] = *(const bf16x8*)(WoT + (size_t)c * 512 + h * 64 + kk * 32 + g * 8);
    }
#pragma unroll
    for (int ct = 0; ct < 4; ++ct)
      bfr[ct] = *(const bf16x8*)&kvs[ct * 16 + li][kk * 32 + g * 8];
#pragma unroll
    for (int rt = 0; rt < 4; ++rt)
#pragma unroll
      for (int ct = 0; ct < 4; ++ct)
        acc[rt][ct] = MFMA16(af[rt], bfr[ct], acc[rt][ct]);
  }
  bf16* o = WfT + (size_t)m * 262144;
#pragma unroll
  for (int rt = 0; rt < 4; ++rt)
#pragma unroll
    for (int ct = 0; ct < 4; ++ct)
#pragma unroll
      for (int q = 0; q < 4; ++q) {
        const int c = wave * 64 + rt * 16 + g * 4 + q;
        const int r = h * 64 + ct * 16 + li;
        o[(size_t)c * 512 + r] = (bf16)acc[rt][ct][q];
      }
}

// ---------------- K4: out = Q @ Wfused[m] + bo, both operands gload_lds, BK=64 ----------------
// 512 blocks (64 rows), 512 thr = 8 waves; wave w owns cols w*64..+64.
// 8-slot XOR swizzle: storage row r slot s holds chunk s ^ (r&7); read slot = c ^ (r&7).
__global__ __launch_bounds__(512) void k_out(const bf16* __restrict__ Q, const bf16* __restrict__ WfT,
                                             const float* __restrict__ bo, float* __restrict__ out)
{
  const int rb = blockIdx.x;
  const int m  = rb >> 5;                      // 32 row-blocks per m
  const bf16* Bm = WfT + (size_t)m * 262144;

  __shared__ bf16 As[64 * 64];    // 8 KB, linear [64][64]
  __shared__ bf16 Bs[512 * 64];   // 64 KB, linear [512][64]

  const int t = threadIdx.x, lane = t & 63, w = t >> 6;
  const int g = lane >> 4, li = lane & 15;
  const size_t arow = (size_t)rb * 64;

  const int lr = lane >> 3, ls = lane & 7;
  const int schunk = ls ^ lr;                  // source chunk (involution, lr = row&7)
  const bf16* asrc = Q  + (arow + w * 8 + lr) * 512 + schunk * 8;
  const bf16* bsrc = Bm + (size_t)(w * 64 + lr) * 512 + schunk * 8;
  char* adst = (char*)&As[0] + w * 1024;
  char* bdst = (char*)&Bs[0] + w * 8192;

  f32x4 acc[4][4] = {};

  for (int kt = 0; kt < 8; ++kt) {
    __syncthreads();
    glds16(asrc + kt * 64, adst);              // A: 1 issue/wave (8 rows)
#pragma unroll
    for (int j = 0; j < 8; ++j)                // B: 8 issues/wave (64 rows)
      glds16(bsrc + (size_t)j * 8 * 512 + kt * 64, bdst + j * 1024);
    __syncthreads();
#pragma unroll
    for (int ks = 0; ks < 2; ++ks) {
      bf16x8 af[4], bfr[4];
#pragma unroll
      for (int rt = 0; rt < 4; ++rt) {
        const int r = rt * 16 + li;
        af[rt] = *(const bf16x8*)&As[r * 64 + ((ks * 4 + g) ^ (li & 7)) * 8];
      }
#pragma unroll
      for (int ct = 0; ct < 4; ++ct) {
        const int c = w * 64 + ct * 16 + li;
        bfr[ct] = *(const bf16x8*)&Bs[c * 64 + ((ks * 4 + g) ^ (li & 7)) * 8];
      }
#pragma unroll
      for (int rt = 0; rt < 4; ++rt)
#pragma unroll
        for (int ct = 0; ct < 4; ++ct)
          acc[rt][ct] = MFMA16(af[rt], bfr[ct], acc[rt][ct]);
    }
  }

  float bv[4];
#pragma unroll
  for (int ct = 0; ct < 4; ++ct) bv[ct] = bo[w * 64 + ct * 16 + li];
#pragma unroll
  for (int rt = 0; rt < 4; ++rt)
#pragma unroll
    for (int q = 0; q < 4; ++q) {
      float* o = out + (arow + rt * 16 + g * 4 + q) * 512 + w * 64 + li;
      o[0]  = acc[rt][0][q] + bv[0];
      o[16] = acc[rt][1][q] + bv[1];
      o[32] = acc[rt][2][q] + bv[2];
      o[48] = acc[rt][3][q] + bv[3];
    }
}

// ---------------- host ----------------
extern "C" void kernel_launch(void* const* d_in, const int* in_sizes, int n_in,
                              void* d_out, int out_size, void* d_ws, size_t ws_size,
                              hipStream_t stream)
{
  const float* xq = (const float*)d_in[0];
  const float* xk = (const float*)d_in[1];
  const float* xv = (const float*)d_in[2];
  const float* Wq = (const float*)d_in[3];
  const float* Wk = (const float*)d_in[4];
  const float* Wv = (const float*)d_in[5];
  const float* Wo = (const float*)d_in[6];
  const float* bo = (const float*)d_in[7];
  float* out = (float*)d_out;

  char* ws = (char*)d_ws;
  const size_t WT_BYTES  = 512 * 512 * 2;           // 512 KiB each
  const size_t QKV_BYTES = (size_t)32768 * 512 * 2; // 32 MiB each
  bf16*  WqT = (bf16*)(ws);
  bf16*  WkT = (bf16*)(ws + WT_BYTES);
  bf16*  WvT = (bf16*)(ws + 2 * WT_BYTES);
  bf16*  WoT = (bf16*)(ws + 3 * WT_BYTES);
  bf16*  Qb  = (bf16*)(ws + 4 * WT_BYTES);
  bf16*  Kb  = (bf16*)(ws + 4 * WT_BYTES + QKV_BYTES);
  bf16*  Vb  = (bf16*)(ws + 4 * WT_BYTES + 2 * QKV_BYTES);
  float* kvp = (float*)(ws + 4 * WT_BYTES + 3 * QKV_BYTES);  // 8 MiB
  bf16*  WfT = Kb;  // overlay: Kb dead after k_kv

  k_prep  <<<dim3(8, 8, 4),   256, 0, stream>>>(Wq, Wk, Wv, Wo, WqT, WkT, WvT, WoT);
  k_qkv   <<<dim3(512, 1, 3), 512, 0, stream>>>(xq, xk, xv, WqT, WkT, WvT, Qb, Kb, Vb);
  k_kv    <<<dim3(128, 4),    256, 0, stream>>>(Kb, Vb, kvp);
  k_wfused<<<dim3(128),       512, 0, stream>>>(kvp, WoT, WfT);
  k_out   <<<dim3(512),       512, 0, stream>>>(Qb, WfT, bo, out);
}